// Round 6
// baseline (3839.698 us; speedup 1.0000x reference)
//
#include <hip/hip_runtime.h>
#include <hip/hip_bf16.h>

// Problem constants: B=4, N=2048, DIM=512, H=8, DH=64, ORDER=3, TOPK=64, INNER=512
#define SLOTS 80   // sparse slots per row (64 + tie headroom)

// ---------------------------------------------------------------------------
// K1/K4: fp32 tiled GEMM with bias: C = A(MxK) @ B(KxN) + bias(N)
// BM=BN=128, BK=16, 256 threads, 8x8 per thread. (unchanged)
// ---------------------------------------------------------------------------
__global__ __launch_bounds__(256)
void sgemm_bias(const float* __restrict__ A, const float* __restrict__ Bm,
                const float* __restrict__ bias, float* __restrict__ C,
                int M, int N, int K)
{
    __shared__ float As[16][132];
    __shared__ float Bs[16][132];

    const int t  = threadIdx.x;
    const int tx = t & 15, ty = t >> 4;
    const int bm = blockIdx.y << 7, bn = blockIdx.x << 7;

    const int arow = t >> 2,  ak4 = (t & 3) << 2;
    const int bkr  = t >> 5,  bc4 = (t & 31) << 2;

    float4 pa[2], pb[2];
#pragma unroll
    for (int s = 0; s < 2; ++s) {
        pa[s] = *(const float4*)&A[(size_t)(bm + arow + (s << 6)) * K + ak4];
        pb[s] = *(const float4*)&Bm[(size_t)(bkr + (s << 3)) * N + bn + bc4];
    }

    float acc[8][8] = {};

    for (int k0 = 0; k0 < K; k0 += 16) {
        __syncthreads();
#pragma unroll
        for (int s = 0; s < 2; ++s) {
            const int ar = arow + (s << 6);
            As[ak4 + 0][ar] = pa[s].x;
            As[ak4 + 1][ar] = pa[s].y;
            As[ak4 + 2][ar] = pa[s].z;
            As[ak4 + 3][ar] = pa[s].w;
            *(float4*)&Bs[bkr + (s << 3)][bc4] = pb[s];
        }
        __syncthreads();
        if (k0 + 16 < K) {
#pragma unroll
            for (int s = 0; s < 2; ++s) {
                pa[s] = *(const float4*)&A[(size_t)(bm + arow + (s << 6)) * K + k0 + 16 + ak4];
                pb[s] = *(const float4*)&Bm[(size_t)(k0 + 16 + bkr + (s << 3)) * N + bn + bc4];
            }
        }
#pragma unroll
        for (int kk = 0; kk < 16; ++kk) {
            float4 a0 = *(const float4*)&As[kk][(ty << 3) + 0];
            float4 a1 = *(const float4*)&As[kk][(ty << 3) + 4];
            float4 b0 = *(const float4*)&Bs[kk][(tx << 2)];
            float4 b1 = *(const float4*)&Bs[kk][64 + (tx << 2)];
            float ar[8] = {a0.x, a0.y, a0.z, a0.w, a1.x, a1.y, a1.z, a1.w};
            float br[8] = {b0.x, b0.y, b0.z, b0.w, b1.x, b1.y, b1.z, b1.w};
#pragma unroll
            for (int i = 0; i < 8; ++i)
#pragma unroll
                for (int j = 0; j < 8; ++j)
                    acc[i][j] = fmaf(ar[i], br[j], acc[i][j]);
        }
    }

    float bb[8];
#pragma unroll
    for (int j = 0; j < 4; ++j) {
        bb[j]     = bias[bn + (tx << 2) + j];
        bb[j + 4] = bias[bn + 64 + (tx << 2) + j];
    }
#pragma unroll
    for (int i = 0; i < 8; ++i) {
        const size_t row = (size_t)(bm + (ty << 3) + i);
        float4 o0 = {acc[i][0] + bb[0], acc[i][1] + bb[1], acc[i][2] + bb[2], acc[i][3] + bb[3]};
        float4 o1 = {acc[i][4] + bb[4], acc[i][5] + bb[5], acc[i][6] + bb[6], acc[i][7] + bb[7]};
        *(float4*)&C[row * N + bn + (tx << 2)]      = o0;
        *(float4*)&C[row * N + bn + 64 + (tx << 2)] = o1;
    }
}

// ---------------------------------------------------------------------------
// K2 v6: row-stationary scores + fused exact top-k, sized for a HARD 128-VGPR
// budget: wave owns 2 rows (acc[2][32] = 64 regs), and phase B runs with NO
// extra uv[] array -- scores are transformed in place to their monotonic-uint
// bit pattern (bitcast only, exact), bisected, then inverted for exp.
// All register-array indices are compile-time literals (rule #20).
// K streamed via double-buffered swizzled LDS tiles (128 cols x 64 d).
// Per-score fmaf chain d-ascending 0..63 -> same numerics as R2-R5.
// ---------------------------------------------------------------------------
__global__ __launch_bounds__(256, 2)
void scores_topk(const float* __restrict__ qkv, float* __restrict__ svals,
                 unsigned short* __restrict__ sidx, int* __restrict__ scnt)
{
    __shared__ float kt[16384];   // 2 x (128 cols x 64 d), 16B-slot swizzled

    const int t    = threadIdx.x;
    const int lane = t & 63;
    const int wid  = t >> 6;
    const int bh   = blockIdx.y;
    const int b    = bh >> 3, h = bh & 7;
    const size_t rowbase = (size_t)b * 2048;
    const int qoff = h << 6;
    const int koff = 512 + (h << 6);
    const int swz  = lane & 7;

    // wave's 2 rows (uniform): block covers 8 rows
    int wr0 = (blockIdx.x << 3) + (wid << 1);
    wr0 = __builtin_amdgcn_readfirstlane(wr0);
    const float* qb0 = qkv + (rowbase + (size_t)(wr0 + 0)) * 1536 + qoff;
    const float* qb1 = qkv + (rowbase + (size_t)(wr0 + 1)) * 1536 + qoff;

    const int sl = t & 15;
    float4 pre[8];

    auto stage_load = [&](int tn) {
#pragma unroll
        for (int i = 0; i < 8; ++i) {
            const int c = (t >> 4) + (i << 4);
            pre[i] = *(const float4*)
                &qkv[(rowbase + (size_t)((tn << 7) + c)) * 1536 + koff + (sl << 2)];
        }
    };
    auto stage_write = [&](int bufi) {
#pragma unroll
        for (int i = 0; i < 8; ++i) {
            const int c = (t >> 4) + (i << 4);
            *(float4*)&kt[(bufi << 13) + (c << 6) + ((sl ^ (c & 7)) << 2)] = pre[i];
        }
    };

    stage_load(0);
    stage_write(0);
    stage_load(1);
    __syncthreads();         // buf0 ready

    float acc[2][32];
#pragma unroll
    for (int r = 0; r < 2; ++r)
#pragma unroll
        for (int m = 0; m < 32; ++m) acc[r][m] = 0.f;

#define ROWFMA(RQ, QB, TT)                                                     \
    {                                                                          \
        const float4 q4 = *(const float4*)&QB[s << 2];                         \
        float a = acc[RQ][2 * (TT)];                                           \
        a = fmaf(q4.x, ka.x, a); a = fmaf(q4.y, ka.y, a);                      \
        a = fmaf(q4.z, ka.z, a); a = fmaf(q4.w, ka.w, a);                      \
        acc[RQ][2 * (TT)] = a;                                                 \
        float c2 = acc[RQ][2 * (TT) + 1];                                      \
        c2 = fmaf(q4.x, kb.x, c2); c2 = fmaf(q4.y, kb.y, c2);                  \
        c2 = fmaf(q4.z, kb.z, c2); c2 = fmaf(q4.w, kb.w, c2);                  \
        acc[RQ][2 * (TT) + 1] = c2;                                            \
    }

#define STEP(TT)                                                               \
    {                                                                          \
        const int cb = ((TT) & 1) << 13;                                       \
        _Pragma("unroll")                                                      \
        for (int s = 0; s < 16; ++s) {                                         \
            const float4 ka = *(const float4*)&kt[cb + (lane << 6) + ((s ^ swz) << 2)];        \
            const float4 kb = *(const float4*)&kt[cb + 4096 + (lane << 6) + ((s ^ swz) << 2)]; \
            ROWFMA(0, qb0, TT) ROWFMA(1, qb1, TT)                              \
        }                                                                      \
        if ((TT) < 15) {                                                       \
            stage_write(1 - ((TT) & 1));                                       \
            if ((TT) < 14) stage_load((TT) + 2);                               \
            __syncthreads();                                                   \
        }                                                                      \
    }

    STEP(0)  STEP(1)  STEP(2)  STEP(3)
    STEP(4)  STEP(5)  STEP(6)  STEP(7)
    STEP(8)  STEP(9)  STEP(10) STEP(11)
    STEP(12) STEP(13) STEP(14) STEP(15)
#undef STEP
#undef ROWFMA

    // phase B per row; acc[RQ][m] is reused in place:
    //   stage 1: acc holds monotonic-uint(score*0.125) as raw bits
    //   stage 2: acc holds exp(score - max) (0.0f for dropped)
    const unsigned long long pre64 = (1ull << lane) - 1ull;

#define PHASEB(RQ)                                                             \
    {                                                                          \
        _Pragma("unroll")                                                      \
        for (int m = 0; m < 32; ++m) {                                         \
            const float x = acc[RQ][m] * 0.125f;                               \
            const unsigned bx = __float_as_uint(x);                            \
            acc[RQ][m] = __uint_as_float(                                      \
                bx ^ (unsigned)(((int)bx >> 31) | 0x80000000));                \
        }                                                                      \
        unsigned lo = 0;                                                       \
        _Pragma("unroll 1")                                                    \
        for (int bit = 31; bit >= 0; --bit) {                                  \
            const unsigned mid = lo | (1u << bit);                             \
            int c = 0;                                                         \
            _Pragma("unroll")                                                  \
            for (int m = 0; m < 32; ++m)                                       \
                c += __popcll(__ballot(__float_as_uint(acc[RQ][m]) >= mid));   \
            if (c >= 64) lo = mid;                                             \
        }                                                                      \
        unsigned um = 0;                                                       \
        _Pragma("unroll")                                                      \
        for (int m = 0; m < 32; ++m) {                                         \
            const unsigned u = __float_as_uint(acc[RQ][m]);                    \
            um = u > um ? u : um;                                              \
        }                                                                      \
        _Pragma("unroll")                                                      \
        for (int off = 1; off < 64; off <<= 1) {                               \
            const unsigned o = (unsigned)__shfl_xor((int)um, off, 64);         \
            um = o > um ? o : um;                                              \
        }                                                                      \
        const unsigned mbm = (um & 0x80000000u) ? (um ^ 0x80000000u) : ~um;    \
        const float Mx = __uint_as_float(mbm);                                 \
        float zs = 0.f;                                                        \
        _Pragma("unroll")                                                      \
        for (int m = 0; m < 32; ++m) {                                         \
            const unsigned u = __float_as_uint(acc[RQ][m]);                    \
            const bool keep = u >= lo;                                         \
            const unsigned xb = (u & 0x80000000u) ? (u ^ 0x80000000u) : ~u;    \
            const float ex = keep ? __expf(__uint_as_float(xb) - Mx) : 0.f;    \
            acc[RQ][m] = ex;                                                   \
            zs += ex;                                                          \
        }                                                                      \
        _Pragma("unroll")                                                      \
        for (int off = 1; off < 64; off <<= 1) zs += __shfl_xor(zs, off, 64);  \
        const float zinv = 1.0f / zs;                                          \
        const size_t grow = (size_t)bh * 2048 + wr0 + (RQ);                    \
        float* vd          = svals + grow * SLOTS;                             \
        unsigned short* id = sidx  + grow * SLOTS;                             \
        int base = 0;                                                          \
        _Pragma("unroll")                                                      \
        for (int m = 0; m < 32; ++m) {                                         \
            const bool keep = acc[RQ][m] > 0.f;                                \
            unsigned long long ball = __ballot(keep);                          \
            if (keep) {                                                        \
                const int my = base + __popcll(ball & pre64);                  \
                if (my < SLOTS) {                                              \
                    vd[my] = acc[RQ][m] * zinv;                                \
                    id[my] = (unsigned short)(((m >> 1) << 7) + ((m & 1) << 6) + lane); \
                }                                                              \
            }                                                                  \
            base += __popcll(ball);                                            \
        }                                                                      \
        if (lane == 0) scnt[grow] = base < SLOTS ? base : SLOTS;               \
    }

    PHASEB(0)
    PHASEB(1)
#undef PHASEB
}

// ---------------------------------------------------------------------------
// K3: sparse attn application (unchanged).
// ---------------------------------------------------------------------------
__global__ __launch_bounds__(256)
void spmm(const float* __restrict__ svals, const unsigned short* __restrict__ sidx,
          const int* __restrict__ scnt, const float* __restrict__ qkv,
          const float* __restrict__ vin, float* __restrict__ vout,
          float* __restrict__ res, const float* __restrict__ alphas_raw, int order)
{
    const int lane = threadIdx.x & 63;
    const int gr   = (blockIdx.x << 2) + (threadIdx.x >> 6);  // 0..65535
    const int bh   = gr >> 11, n = gr & 2047;
    const int b    = bh >> 3,  h = bh & 7;

    const float* vb;
    int stride;
    if (order == 0) { vb = qkv + (size_t)b * 2048 * 1536 + 1024 + (h << 6); stride = 1536; }
    else            { vb = vin + ((size_t)bh << 17);                        stride = 64;   }

    const int cnt = scnt[gr];
    const float* va          = svals + (size_t)gr * SLOTS;
    const unsigned short* ia = sidx  + (size_t)gr * SLOTS;

    float acc = 0.f;
    int j = 0;
    for (; j + 4 <= cnt; j += 4) {
        float a0 = va[j], a1 = va[j + 1], a2 = va[j + 2], a3 = va[j + 3];
        int   i0 = ia[j], i1 = ia[j + 1], i2 = ia[j + 2], i3 = ia[j + 3];
        acc += a0 * vb[(size_t)i0 * stride + lane];
        acc += a1 * vb[(size_t)i1 * stride + lane];
        acc += a2 * vb[(size_t)i2 * stride + lane];
        acc += a3 * vb[(size_t)i3 * stride + lane];
    }
    for (; j < cnt; ++j) acc += va[j] * vb[(size_t)ia[j] * stride + lane];

    if (order < 2) vout[((size_t)gr << 6) + lane] = acc;

    float ar    = alphas_raw[(order << 3) + h];
    float alpha = ar * 0.5f * (1.0f + erff(ar * 0.70710678f));  // exact gelu
    size_t ro = ((size_t)b * 2048 + n) * 512 + (h << 6) + lane;
    float av  = alpha * acc;
    if (order == 0) res[ro] = av;
    else            res[ro] += av;
}

// ---------------------------------------------------------------------------
extern "C" void kernel_launch(void* const* d_in, const int* in_sizes, int n_in,
                              void* d_out, int out_size, void* d_ws, size_t ws_size,
                              hipStream_t stream)
{
    const float* x      = (const float*)d_in[0];
    const float* Wqkv   = (const float*)d_in[1];
    const float* bqkv   = (const float*)d_in[2];
    const float* Wout   = (const float*)d_in[3];
    const float* bout   = (const float*)d_in[4];
    const float* alphas = (const float*)d_in[5];
    float* out = (float*)d_out;

    // workspace layout (bytes)
    char* ws = (char*)d_ws;
    float*          qkvb  = (float*)ws;                       // 8192*1536*4 = 50331648
    float*          svals = (float*)(ws + 50331648);          // 65536*80*4  = 20971520
    unsigned short* sidxp = (unsigned short*)(ws + 71303168); // 65536*80*2  = 10485760
    int*            scntp = (int*)(ws + 81788928);            // 65536*4     = 262144
    float*          v1    = (float*)(ws + 82051072);          // 16777216
    float*          v2    = (float*)(ws + 98828288);          // 16777216
    float*          resb  = (float*)(ws + 115605504);         // 16777216
    if (ws_size < 132382720) return;                          // need ~126 MB

    // K1: qkv = x @ Wqkv + bqkv
    sgemm_bias<<<dim3(1536 / 128, 8192 / 128), 256, 0, stream>>>(
        x, Wqkv, bqkv, qkvb, 8192, 1536, 512);

    // K2: scores (in regs) -> exact top-64(+ties) -> softmax -> sparse rows
    // 256 row-blocks x 8 rows = 2048
    scores_topk<<<dim3(256, 32), 256, 0, stream>>>(qkvb, svals, sidxp, scntp);

    // K3 x3: polynomial filter (sparse A applications)
    spmm<<<16384, 256, 0, stream>>>(svals, sidxp, scntp, qkvb, nullptr, v1, resb, alphas, 0);
    spmm<<<16384, 256, 0, stream>>>(svals, sidxp, scntp, qkvb, v1, v2, resb, alphas, 1);
    spmm<<<16384, 256, 0, stream>>>(svals, sidxp, scntp, qkvb, v2, nullptr, resb, alphas, 2);

    // K4: out = res @ Wout + bout
    sgemm_bias<<<dim3(512 / 128, 8192 / 128), 256, 0, stream>>>(
        resb, Wout, bout, out, 8192, 512, 512);
}

// Round 7
// 2446.560 us; speedup vs baseline: 1.5694x; 1.5694x over previous
//
#include <hip/hip_runtime.h>
#include <hip/hip_bf16.h>

// Problem constants: B=4, N=2048, DIM=512, H=8, DH=64, ORDER=3, TOPK=64, INNER=512
#define SLOTS 80   // sparse slots per row (64 + tie headroom)

// ---------------------------------------------------------------------------
// K1/K4: fp32 tiled GEMM with bias: C = A(MxK) @ B(KxN) + bias(N)
// BM=BN=128, BK=16, 256 threads, 8x8 per thread. (unchanged)
// ---------------------------------------------------------------------------
__global__ __launch_bounds__(256)
void sgemm_bias(const float* __restrict__ A, const float* __restrict__ Bm,
                const float* __restrict__ bias, float* __restrict__ C,
                int M, int N, int K)
{
    __shared__ float As[16][132];
    __shared__ float Bs[16][132];

    const int t  = threadIdx.x;
    const int tx = t & 15, ty = t >> 4;
    const int bm = blockIdx.y << 7, bn = blockIdx.x << 7;

    const int arow = t >> 2,  ak4 = (t & 3) << 2;
    const int bkr  = t >> 5,  bc4 = (t & 31) << 2;

    float4 pa[2], pb[2];
#pragma unroll
    for (int s = 0; s < 2; ++s) {
        pa[s] = *(const float4*)&A[(size_t)(bm + arow + (s << 6)) * K + ak4];
        pb[s] = *(const float4*)&Bm[(size_t)(bkr + (s << 3)) * N + bn + bc4];
    }

    float acc[8][8] = {};

    for (int k0 = 0; k0 < K; k0 += 16) {
        __syncthreads();
#pragma unroll
        for (int s = 0; s < 2; ++s) {
            const int ar = arow + (s << 6);
            As[ak4 + 0][ar] = pa[s].x;
            As[ak4 + 1][ar] = pa[s].y;
            As[ak4 + 2][ar] = pa[s].z;
            As[ak4 + 3][ar] = pa[s].w;
            *(float4*)&Bs[bkr + (s << 3)][bc4] = pb[s];
        }
        __syncthreads();
        if (k0 + 16 < K) {
#pragma unroll
            for (int s = 0; s < 2; ++s) {
                pa[s] = *(const float4*)&A[(size_t)(bm + arow + (s << 6)) * K + k0 + 16 + ak4];
                pb[s] = *(const float4*)&Bm[(size_t)(k0 + 16 + bkr + (s << 3)) * N + bn + bc4];
            }
        }
#pragma unroll
        for (int kk = 0; kk < 16; ++kk) {
            float4 a0 = *(const float4*)&As[kk][(ty << 3) + 0];
            float4 a1 = *(const float4*)&As[kk][(ty << 3) + 4];
            float4 b0 = *(const float4*)&Bs[kk][(tx << 2)];
            float4 b1 = *(const float4*)&Bs[kk][64 + (tx << 2)];
            float ar[8] = {a0.x, a0.y, a0.z, a0.w, a1.x, a1.y, a1.z, a1.w};
            float br[8] = {b0.x, b0.y, b0.z, b0.w, b1.x, b1.y, b1.z, b1.w};
#pragma unroll
            for (int i = 0; i < 8; ++i)
#pragma unroll
                for (int j = 0; j < 8; ++j)
                    acc[i][j] = fmaf(ar[i], br[j], acc[i][j]);
        }
    }

    float bb[8];
#pragma unroll
    for (int j = 0; j < 4; ++j) {
        bb[j]     = bias[bn + (tx << 2) + j];
        bb[j + 4] = bias[bn + 64 + (tx << 2) + j];
    }
#pragma unroll
    for (int i = 0; i < 8; ++i) {
        const size_t row = (size_t)(bm + (ty << 3) + i);
        float4 o0 = {acc[i][0] + bb[0], acc[i][1] + bb[1], acc[i][2] + bb[2], acc[i][3] + bb[3]};
        float4 o1 = {acc[i][4] + bb[4], acc[i][5] + bb[5], acc[i][6] + bb[6], acc[i][7] + bb[7]};
        *(float4*)&C[row * N + bn + (tx << 2)]      = o0;
        *(float4*)&C[row * N + bn + 64 + (tx << 2)] = o1;
    }
}

// ---------------------------------------------------------------------------
// K2 v7: row-stationary scores + fused exact top-k.
// Staging now uses global_load_lds (direct HBM->LDS DMA, ZERO staging VGPRs
// -> no spill). LDS dest is linear (thread t -> bytes i*4096 + t*16); the
// XOR swizzle is applied by PRE-SWIZZLING the global source address
// (col c = (t>>4)+16i, d-chunk (t&15)^((t>>4)&7)), producing a bit-identical
// LDS image to R6's reg-staged stage_write. Compute side unchanged.
// Wave owns 2 rows (acc[2][32]); all reg-array indices literal (rule #20).
// ---------------------------------------------------------------------------
__global__ __launch_bounds__(256, 2)
void scores_topk(const float* __restrict__ qkv, float* __restrict__ svals,
                 unsigned short* __restrict__ sidx, int* __restrict__ scnt)
{
    __shared__ float kt[16384];   // 2 x (128 cols x 64 d) tiles, 32 KB each

    const int t    = threadIdx.x;
    const int lane = t & 63;
    const int wid  = t >> 6;
    const int bh   = blockIdx.y;
    const int b    = bh >> 3, h = bh & 7;
    const size_t rowbase = (size_t)b * 2048;
    const int qoff = h << 6;
    const int koff = 512 + (h << 6);
    const int swz  = lane & 7;

    // wave's 2 rows (uniform): block covers 8 rows
    int wr0 = (blockIdx.x << 3) + (wid << 1);
    wr0 = __builtin_amdgcn_readfirstlane(wr0);
    const float* qb0 = qkv + (rowbase + (size_t)(wr0 + 0)) * 1536 + qoff;
    const float* qb1 = qkv + (rowbase + (size_t)(wr0 + 1)) * 1536 + qoff;

    // DMA staging maps: call i, thread t  ->  col c=(t>>4)+16i of the tile,
    // pre-swizzled d-chunk sl2=(t&15)^((t>>4)&7); LDS bytes i*4096 + t*16.
    const int sc  = t >> 4;
    const int sl2 = (t & 15) ^ (sc & 7);

    auto stage = [&](int tn, int bufi) {
#pragma unroll
        for (int i = 0; i < 8; ++i) {
            const float* g = &qkv[(rowbase + (size_t)((tn << 7) + (i << 4) + sc)) * 1536
                                  + koff + (sl2 << 2)];
            float* l = &kt[(bufi << 12) + (bufi << 12) + (i << 10) + (t << 2)];
            __builtin_amdgcn_global_load_lds(
                (const __attribute__((address_space(1))) unsigned int*)g,
                (__attribute__((address_space(3))) unsigned int*)l, 16, 0, 0);
        }
    };

    stage(0, 0);
    __syncthreads();          // drains vmcnt: buf0 ready

    float acc[2][32];
#pragma unroll
    for (int r = 0; r < 2; ++r)
#pragma unroll
        for (int m = 0; m < 32; ++m) acc[r][m] = 0.f;

#define ROWFMA(RQ, QB, TT)                                                     \
    {                                                                          \
        const float4 q4 = *(const float4*)&QB[s << 2];                         \
        float a = acc[RQ][2 * (TT)];                                           \
        a = fmaf(q4.x, ka.x, a); a = fmaf(q4.y, ka.y, a);                      \
        a = fmaf(q4.z, ka.z, a); a = fmaf(q4.w, ka.w, a);                      \
        acc[RQ][2 * (TT)] = a;                                                 \
        float c2 = acc[RQ][2 * (TT) + 1];                                      \
        c2 = fmaf(q4.x, kb.x, c2); c2 = fmaf(q4.y, kb.y, c2);                  \
        c2 = fmaf(q4.z, kb.z, c2); c2 = fmaf(q4.w, kb.w, c2);                  \
        acc[RQ][2 * (TT) + 1] = c2;                                            \
    }

#define STEP(TT)                                                               \
    {                                                                          \
        if ((TT) < 15) stage((TT) + 1, ((TT) + 1) & 1);                        \
        const int cb = ((TT) & 1) << 13;                                       \
        _Pragma("unroll")                                                      \
        for (int s = 0; s < 16; ++s) {                                         \
            const float4 ka = *(const float4*)&kt[cb + (lane << 6) + ((s ^ swz) << 2)];        \
            const float4 kb = *(const float4*)&kt[cb + 4096 + (lane << 6) + ((s ^ swz) << 2)]; \
            ROWFMA(0, qb0, TT) ROWFMA(1, qb1, TT)                              \
        }                                                                      \
        if ((TT) < 15) __syncthreads();                                        \
    }

    STEP(0)  STEP(1)  STEP(2)  STEP(3)
    STEP(4)  STEP(5)  STEP(6)  STEP(7)
    STEP(8)  STEP(9)  STEP(10) STEP(11)
    STEP(12) STEP(13) STEP(14) STEP(15)
#undef STEP
#undef ROWFMA

    // phase B per row; acc[RQ][m] reused in place (monotonic-uint bits, then
    // exp values). No extra register arrays.
    const unsigned long long pre64 = (1ull << lane) - 1ull;

#define PHASEB(RQ)                                                             \
    {                                                                          \
        _Pragma("unroll")                                                      \
        for (int m = 0; m < 32; ++m) {                                         \
            const float x = acc[RQ][m] * 0.125f;                               \
            const unsigned bx = __float_as_uint(x);                            \
            acc[RQ][m] = __uint_as_float(                                      \
                bx ^ (unsigned)(((int)bx >> 31) | 0x80000000));                \
        }                                                                      \
        unsigned lo = 0;                                                       \
        _Pragma("unroll 1")                                                    \
        for (int bit = 31; bit >= 0; --bit) {                                  \
            const unsigned mid = lo | (1u << bit);                             \
            int c = 0;                                                         \
            _Pragma("unroll")                                                  \
            for (int m = 0; m < 32; ++m)                                       \
                c += __popcll(__ballot(__float_as_uint(acc[RQ][m]) >= mid));   \
            if (c >= 64) lo = mid;                                             \
        }                                                                      \
        unsigned um = 0;                                                       \
        _Pragma("unroll")                                                      \
        for (int m = 0; m < 32; ++m) {                                         \
            const unsigned u = __float_as_uint(acc[RQ][m]);                    \
            um = u > um ? u : um;                                              \
        }                                                                      \
        _Pragma("unroll")                                                      \
        for (int off = 1; off < 64; off <<= 1) {                               \
            const unsigned o = (unsigned)__shfl_xor((int)um, off, 64);         \
            um = o > um ? o : um;                                              \
        }                                                                      \
        const unsigned mbm = (um & 0x80000000u) ? (um ^ 0x80000000u) : ~um;    \
        const float Mx = __uint_as_float(mbm);                                 \
        float zs = 0.f;                                                        \
        _Pragma("unroll")                                                      \
        for (int m = 0; m < 32; ++m) {                                         \
            const unsigned u = __float_as_uint(acc[RQ][m]);                    \
            const bool keep = u >= lo;                                         \
            const unsigned xb = (u & 0x80000000u) ? (u ^ 0x80000000u) : ~u;    \
            const float ex = keep ? __expf(__uint_as_float(xb) - Mx) : 0.f;    \
            acc[RQ][m] = ex;                                                   \
            zs += ex;                                                          \
        }                                                                      \
        _Pragma("unroll")                                                      \
        for (int off = 1; off < 64; off <<= 1) zs += __shfl_xor(zs, off, 64);  \
        const float zinv = 1.0f / zs;                                          \
        const size_t grow = (size_t)bh * 2048 + wr0 + (RQ);                    \
        float* vd          = svals + grow * SLOTS;                             \
        unsigned short* id = sidx  + grow * SLOTS;                             \
        int base = 0;                                                          \
        _Pragma("unroll")                                                      \
        for (int m = 0; m < 32; ++m) {                                         \
            const bool keep = acc[RQ][m] > 0.f;                                \
            unsigned long long ball = __ballot(keep);                          \
            if (keep) {                                                        \
                const int my = base + __popcll(ball & pre64);                  \
                if (my < SLOTS) {                                              \
                    vd[my] = acc[RQ][m] * zinv;                                \
                    id[my] = (unsigned short)(((m >> 1) << 7) + ((m & 1) << 6) + lane); \
                }                                                              \
            }                                                                  \
            base += __popcll(ball);                                            \
        }                                                                      \
        if (lane == 0) scnt[grow] = base < SLOTS ? base : SLOTS;               \
    }

    PHASEB(0)
    PHASEB(1)
#undef PHASEB
}

// ---------------------------------------------------------------------------
// K3: sparse attn application (unchanged).
// ---------------------------------------------------------------------------
__global__ __launch_bounds__(256)
void spmm(const float* __restrict__ svals, const unsigned short* __restrict__ sidx,
          const int* __restrict__ scnt, const float* __restrict__ qkv,
          const float* __restrict__ vin, float* __restrict__ vout,
          float* __restrict__ res, const float* __restrict__ alphas_raw, int order)
{
    const int lane = threadIdx.x & 63;
    const int gr   = (blockIdx.x << 2) + (threadIdx.x >> 6);  // 0..65535
    const int bh   = gr >> 11, n = gr & 2047;
    const int b    = bh >> 3,  h = bh & 7;

    const float* vb;
    int stride;
    if (order == 0) { vb = qkv + (size_t)b * 2048 * 1536 + 1024 + (h << 6); stride = 1536; }
    else            { vb = vin + ((size_t)bh << 17);                        stride = 64;   }

    const int cnt = scnt[gr];
    const float* va          = svals + (size_t)gr * SLOTS;
    const unsigned short* ia = sidx  + (size_t)gr * SLOTS;

    float acc = 0.f;
    int j = 0;
    for (; j + 4 <= cnt; j += 4) {
        float a0 = va[j], a1 = va[j + 1], a2 = va[j + 2], a3 = va[j + 3];
        int   i0 = ia[j], i1 = ia[j + 1], i2 = ia[j + 2], i3 = ia[j + 3];
        acc += a0 * vb[(size_t)i0 * stride + lane];
        acc += a1 * vb[(size_t)i1 * stride + lane];
        acc += a2 * vb[(size_t)i2 * stride + lane];
        acc += a3 * vb[(size_t)i3 * stride + lane];
    }
    for (; j < cnt; ++j) acc += va[j] * vb[(size_t)ia[j] * stride + lane];

    if (order < 2) vout[((size_t)gr << 6) + lane] = acc;

    float ar    = alphas_raw[(order << 3) + h];
    float alpha = ar * 0.5f * (1.0f + erff(ar * 0.70710678f));  // exact gelu
    size_t ro = ((size_t)b * 2048 + n) * 512 + (h << 6) + lane;
    float av  = alpha * acc;
    if (order == 0) res[ro] = av;
    else            res[ro] += av;
}

// ---------------------------------------------------------------------------
extern "C" void kernel_launch(void* const* d_in, const int* in_sizes, int n_in,
                              void* d_out, int out_size, void* d_ws, size_t ws_size,
                              hipStream_t stream)
{
    const float* x      = (const float*)d_in[0];
    const float* Wqkv   = (const float*)d_in[1];
    const float* bqkv   = (const float*)d_in[2];
    const float* Wout   = (const float*)d_in[3];
    const float* bout   = (const float*)d_in[4];
    const float* alphas = (const float*)d_in[5];
    float* out = (float*)d_out;

    // workspace layout (bytes)
    char* ws = (char*)d_ws;
    float*          qkvb  = (float*)ws;                       // 8192*1536*4 = 50331648
    float*          svals = (float*)(ws + 50331648);          // 65536*80*4  = 20971520
    unsigned short* sidxp = (unsigned short*)(ws + 71303168); // 65536*80*2  = 10485760
    int*            scntp = (int*)(ws + 81788928);            // 65536*4     = 262144
    float*          v1    = (float*)(ws + 82051072);          // 16777216
    float*          v2    = (float*)(ws + 98828288);          // 16777216
    float*          resb  = (float*)(ws + 115605504);         // 16777216
    if (ws_size < 132382720) return;                          // need ~126 MB

    // K1: qkv = x @ Wqkv + bqkv
    sgemm_bias<<<dim3(1536 / 128, 8192 / 128), 256, 0, stream>>>(
        x, Wqkv, bqkv, qkvb, 8192, 1536, 512);

    // K2: scores (in regs) -> exact top-64(+ties) -> softmax -> sparse rows
    // 256 row-blocks x 8 rows = 2048
    scores_topk<<<dim3(256, 32), 256, 0, stream>>>(qkvb, svals, sidxp, scntp);

    // K3 x3: polynomial filter (sparse A applications)
    spmm<<<16384, 256, 0, stream>>>(svals, sidxp, scntp, qkvb, nullptr, v1, resb, alphas, 0);
    spmm<<<16384, 256, 0, stream>>>(svals, sidxp, scntp, qkvb, v1, v2, resb, alphas, 1);
    spmm<<<16384, 256, 0, stream>>>(svals, sidxp, scntp, qkvb, v2, nullptr, resb, alphas, 2);

    // K4: out = res @ Wout + bout
    sgemm_bias<<<dim3(512 / 128, 8192 / 128), 256, 0, stream>>>(
        resb, Wout, bout, out, 8192, 512, 512);
}

// Round 8
// 1618.456 us; speedup vs baseline: 2.3724x; 1.5117x over previous
//
#include <hip/hip_runtime.h>
#include <hip/hip_bf16.h>

// Problem constants: B=4, N=2048, DIM=512, H=8, DH=64, ORDER=3, TOPK=64, INNER=512
#define SLOTS 80   // sparse slots per row (64 + tie headroom)

// ---------------------------------------------------------------------------
// K1/K4: fp32 tiled GEMM with bias: C = A(MxK) @ B(KxN) + bias(N)
// BM=BN=128, BK=16, 256 threads, 8x8 per thread. (unchanged)
// ---------------------------------------------------------------------------
__global__ __launch_bounds__(256)
void sgemm_bias(const float* __restrict__ A, const float* __restrict__ Bm,
                const float* __restrict__ bias, float* __restrict__ C,
                int M, int N, int K)
{
    __shared__ float As[16][132];
    __shared__ float Bs[16][132];

    const int t  = threadIdx.x;
    const int tx = t & 15, ty = t >> 4;
    const int bm = blockIdx.y << 7, bn = blockIdx.x << 7;

    const int arow = t >> 2,  ak4 = (t & 3) << 2;
    const int bkr  = t >> 5,  bc4 = (t & 31) << 2;

    float4 pa[2], pb[2];
#pragma unroll
    for (int s = 0; s < 2; ++s) {
        pa[s] = *(const float4*)&A[(size_t)(bm + arow + (s << 6)) * K + ak4];
        pb[s] = *(const float4*)&Bm[(size_t)(bkr + (s << 3)) * N + bn + bc4];
    }

    float acc[8][8] = {};

    for (int k0 = 0; k0 < K; k0 += 16) {
        __syncthreads();
#pragma unroll
        for (int s = 0; s < 2; ++s) {
            const int ar = arow + (s << 6);
            As[ak4 + 0][ar] = pa[s].x;
            As[ak4 + 1][ar] = pa[s].y;
            As[ak4 + 2][ar] = pa[s].z;
            As[ak4 + 3][ar] = pa[s].w;
            *(float4*)&Bs[bkr + (s << 3)][bc4] = pb[s];
        }
        __syncthreads();
        if (k0 + 16 < K) {
#pragma unroll
            for (int s = 0; s < 2; ++s) {
                pa[s] = *(const float4*)&A[(size_t)(bm + arow + (s << 6)) * K + k0 + 16 + ak4];
                pb[s] = *(const float4*)&Bm[(size_t)(k0 + 16 + bkr + (s << 3)) * N + bn + bc4];
            }
        }
#pragma unroll
        for (int kk = 0; kk < 16; ++kk) {
            float4 a0 = *(const float4*)&As[kk][(ty << 3) + 0];
            float4 a1 = *(const float4*)&As[kk][(ty << 3) + 4];
            float4 b0 = *(const float4*)&Bs[kk][(tx << 2)];
            float4 b1 = *(const float4*)&Bs[kk][64 + (tx << 2)];
            float ar[8] = {a0.x, a0.y, a0.z, a0.w, a1.x, a1.y, a1.z, a1.w};
            float br[8] = {b0.x, b0.y, b0.z, b0.w, b1.x, b1.y, b1.z, b1.w};
#pragma unroll
            for (int i = 0; i < 8; ++i)
#pragma unroll
                for (int j = 0; j < 8; ++j)
                    acc[i][j] = fmaf(ar[i], br[j], acc[i][j]);
        }
    }

    float bb[8];
#pragma unroll
    for (int j = 0; j < 4; ++j) {
        bb[j]     = bias[bn + (tx << 2) + j];
        bb[j + 4] = bias[bn + 64 + (tx << 2) + j];
    }
#pragma unroll
    for (int i = 0; i < 8; ++i) {
        const size_t row = (size_t)(bm + (ty << 3) + i);
        float4 o0 = {acc[i][0] + bb[0], acc[i][1] + bb[1], acc[i][2] + bb[2], acc[i][3] + bb[3]};
        float4 o1 = {acc[i][4] + bb[4], acc[i][5] + bb[5], acc[i][6] + bb[6], acc[i][7] + bb[7]};
        *(float4*)&C[row * N + bn + (tx << 2)]      = o0;
        *(float4*)&C[row * N + bn + 64 + (tx << 2)] = o1;
    }
}

// ---------------------------------------------------------------------------
// K2 v8: 512-thread block owns 16 rows of one (b,h). No K staging: each lane
// reads its 4 K-columns directly from global (L1/L2-cached; block reads the
// 512KB panel exactly once). acc[16][4] (64 VGPR) carried across a RUNTIME
// s-loop (sgemm-proven pattern: literal acc indices, only addresses depend
// on s). Scores flushed to S[16][2048] LDS (128 KB); phase B = R2's proven
// fv/uv bisection, 2 rows/wave. XCD-affine block mapping keeps all row-blocks
// of one (b,h) on one XCD -> K panel stays L2-resident.
// Per-score fmaf chain d-ascending 0..63 -> bit-identical to R2-R7.
// ---------------------------------------------------------------------------
__global__ __launch_bounds__(512, 2)
void scores_topk(const float* __restrict__ qkv, float* __restrict__ svals,
                 unsigned short* __restrict__ sidx, int* __restrict__ scnt)
{
    __shared__ float S[16][2048];   // 128 KiB

    const int t    = threadIdx.x;
    const int lane = t & 63;
    const int wid  = t >> 6;                        // 0..7
    const int id   = blockIdx.x;                    // 0..4095
    const int bh   = ((id >> 10) << 3) | (id & 7);  // XCD-affine, bijective
    const int rowblk = (id >> 3) & 127;
    const int b = bh >> 3, h = bh & 7;
    const size_t rowbase = (size_t)b * 2048;
    const int r0 = rowblk << 4;                     // block's 16 rows

    // q base for the block's rows (uniform across lanes -> broadcast loads)
    const float* qb = qkv + (rowbase + r0) * 1536 + (h << 6);
    // lane's 4 K-columns: cbase + {0,64,128,192}
    const int cbase = (wid << 8) + lane;
    const float* k0 = qkv + (rowbase + (size_t)cbase) * 1536 + 512 + (h << 6);

    float acc[16][4];
#pragma unroll
    for (int r = 0; r < 16; ++r)
#pragma unroll
        for (int c = 0; c < 4; ++c) acc[r][c] = 0.f;

#pragma unroll 1
    for (int s = 0; s < 16; ++s) {
        const float4 ka = *(const float4*)&k0[(s << 2)];
        const float4 kb = *(const float4*)&k0[64 * 1536 + (s << 2)];
        const float4 kc = *(const float4*)&k0[128 * 1536 + (s << 2)];
        const float4 kd = *(const float4*)&k0[192 * 1536 + (s << 2)];
#pragma unroll
        for (int r = 0; r < 16; ++r) {
            const float4 q4 = *(const float4*)&qb[r * 1536 + (s << 2)];
            float a0 = acc[r][0], a1 = acc[r][1], a2 = acc[r][2], a3 = acc[r][3];
            a0 = fmaf(q4.x, ka.x, a0); a0 = fmaf(q4.y, ka.y, a0);
            a0 = fmaf(q4.z, ka.z, a0); a0 = fmaf(q4.w, ka.w, a0);
            a1 = fmaf(q4.x, kb.x, a1); a1 = fmaf(q4.y, kb.y, a1);
            a1 = fmaf(q4.z, kb.z, a1); a1 = fmaf(q4.w, kb.w, a1);
            a2 = fmaf(q4.x, kc.x, a2); a2 = fmaf(q4.y, kc.y, a2);
            a2 = fmaf(q4.z, kc.z, a2); a2 = fmaf(q4.w, kc.w, a2);
            a3 = fmaf(q4.x, kd.x, a3); a3 = fmaf(q4.y, kd.y, a3);
            a3 = fmaf(q4.z, kd.z, a3); a3 = fmaf(q4.w, kd.w, a3);
            acc[r][0] = a0; acc[r][1] = a1; acc[r][2] = a2; acc[r][3] = a3;
        }
    }

    // flush scaled scores to S (contiguous per-lane stores: conflict-free)
#pragma unroll
    for (int r = 0; r < 16; ++r) {
        S[r][cbase +   0] = acc[r][0] * 0.125f;
        S[r][cbase +  64] = acc[r][1] * 0.125f;
        S[r][cbase + 128] = acc[r][2] * 0.125f;
        S[r][cbase + 192] = acc[r][3] * 0.125f;
    }
    __syncthreads();

    // phase B: per wave, 2 rows; exact 64th-largest via bit bisection (R2's
    // proven-clean structure; fv/uv fresh per row, compaction fully unrolled)
    const unsigned long long pre64 = (1ull << lane) - 1ull;

#define PHASEB(RQ)                                                             \
    {                                                                          \
        const int rr = (wid << 1) + (RQ);                                      \
        float    fv[32];                                                       \
        unsigned uv[32];                                                       \
        _Pragma("unroll")                                                      \
        for (int m = 0; m < 32; ++m) {                                         \
            const float x = S[rr][lane + (m << 6)];                            \
            fv[m] = x;                                                         \
            const unsigned bx = __float_as_uint(x);                            \
            uv[m] = bx ^ (unsigned)(((int)bx >> 31) | 0x80000000);             \
        }                                                                      \
        unsigned lo = 0;                                                       \
        _Pragma("unroll 1")                                                    \
        for (int bit = 31; bit >= 0; --bit) {                                  \
            const unsigned mid = lo | (1u << bit);                             \
            int c = 0;                                                         \
            _Pragma("unroll")                                                  \
            for (int m = 0; m < 32; ++m)                                       \
                c += __popcll(__ballot(uv[m] >= mid));                         \
            if (c >= 64) lo = mid;                                             \
        }                                                                      \
        unsigned um = 0;                                                       \
        _Pragma("unroll")                                                      \
        for (int m = 0; m < 32; ++m) um = uv[m] > um ? uv[m] : um;             \
        _Pragma("unroll")                                                      \
        for (int off = 1; off < 64; off <<= 1) {                               \
            const unsigned o = (unsigned)__shfl_xor((int)um, off, 64);         \
            um = o > um ? o : um;                                              \
        }                                                                      \
        const unsigned mbm = (um & 0x80000000u) ? (um ^ 0x80000000u) : ~um;    \
        const float Mx = __uint_as_float(mbm);                                 \
        float zs = 0.f;                                                        \
        _Pragma("unroll")                                                      \
        for (int m = 0; m < 32; ++m) {                                         \
            const bool keep = uv[m] >= lo;                                     \
            const float ex = keep ? __expf(fv[m] - Mx) : 0.f;                  \
            fv[m] = ex;                                                        \
            zs += ex;                                                          \
        }                                                                      \
        _Pragma("unroll")                                                      \
        for (int off = 1; off < 64; off <<= 1) zs += __shfl_xor(zs, off, 64);  \
        const float zinv = 1.0f / zs;                                          \
        const size_t grow = (size_t)bh * 2048 + r0 + rr;                       \
        float* vd          = svals + grow * SLOTS;                             \
        unsigned short* id = sidx  + grow * SLOTS;                             \
        int base = 0;                                                          \
        _Pragma("unroll")                                                      \
        for (int m = 0; m < 32; ++m) {                                         \
            const bool keep = uv[m] >= lo;                                     \
            unsigned long long ball = __ballot(keep);                          \
            if (keep) {                                                        \
                const int my = base + __popcll(ball & pre64);                  \
                if (my < SLOTS) {                                              \
                    vd[my] = fv[m] * zinv;                                     \
                    id[my] = (unsigned short)(lane + (m << 6));                \
                }                                                              \
            }                                                                  \
            base += __popcll(ball);                                            \
        }                                                                      \
        if (lane == 0) scnt[grow] = base < SLOTS ? base : SLOTS;               \
    }

    PHASEB(0)
    PHASEB(1)
#undef PHASEB
}

// ---------------------------------------------------------------------------
// K3: sparse attn application (unchanged).
// ---------------------------------------------------------------------------
__global__ __launch_bounds__(256)
void spmm(const float* __restrict__ svals, const unsigned short* __restrict__ sidx,
          const int* __restrict__ scnt, const float* __restrict__ qkv,
          const float* __restrict__ vin, float* __restrict__ vout,
          float* __restrict__ res, const float* __restrict__ alphas_raw, int order)
{
    const int lane = threadIdx.x & 63;
    const int gr   = (blockIdx.x << 2) + (threadIdx.x >> 6);  // 0..65535
    const int bh   = gr >> 11, n = gr & 2047;
    const int b    = bh >> 3,  h = bh & 7;

    const float* vb;
    int stride;
    if (order == 0) { vb = qkv + (size_t)b * 2048 * 1536 + 1024 + (h << 6); stride = 1536; }
    else            { vb = vin + ((size_t)bh << 17);                        stride = 64;   }

    const int cnt = scnt[gr];
    const float* va          = svals + (size_t)gr * SLOTS;
    const unsigned short* ia = sidx  + (size_t)gr * SLOTS;

    float acc = 0.f;
    int j = 0;
    for (; j + 4 <= cnt; j += 4) {
        float a0 = va[j], a1 = va[j + 1], a2 = va[j + 2], a3 = va[j + 3];
        int   i0 = ia[j], i1 = ia[j + 1], i2 = ia[j + 2], i3 = ia[j + 3];
        acc += a0 * vb[(size_t)i0 * stride + lane];
        acc += a1 * vb[(size_t)i1 * stride + lane];
        acc += a2 * vb[(size_t)i2 * stride + lane];
        acc += a3 * vb[(size_t)i3 * stride + lane];
    }
    for (; j < cnt; ++j) acc += va[j] * vb[(size_t)ia[j] * stride + lane];

    if (order < 2) vout[((size_t)gr << 6) + lane] = acc;

    float ar    = alphas_raw[(order << 3) + h];
    float alpha = ar * 0.5f * (1.0f + erff(ar * 0.70710678f));  // exact gelu
    size_t ro = ((size_t)b * 2048 + n) * 512 + (h << 6) + lane;
    float av  = alpha * acc;
    if (order == 0) res[ro] = av;
    else            res[ro] += av;
}

// ---------------------------------------------------------------------------
extern "C" void kernel_launch(void* const* d_in, const int* in_sizes, int n_in,
                              void* d_out, int out_size, void* d_ws, size_t ws_size,
                              hipStream_t stream)
{
    const float* x      = (const float*)d_in[0];
    const float* Wqkv   = (const float*)d_in[1];
    const float* bqkv   = (const float*)d_in[2];
    const float* Wout   = (const float*)d_in[3];
    const float* bout   = (const float*)d_in[4];
    const float* alphas = (const float*)d_in[5];
    float* out = (float*)d_out;

    // workspace layout (bytes)
    char* ws = (char*)d_ws;
    float*          qkvb  = (float*)ws;                       // 8192*1536*4 = 50331648
    float*          svals = (float*)(ws + 50331648);          // 65536*80*4  = 20971520
    unsigned short* sidxp = (unsigned short*)(ws + 71303168); // 65536*80*2  = 10485760
    int*            scntp = (int*)(ws + 81788928);            // 65536*4     = 262144
    float*          v1    = (float*)(ws + 82051072);          // 16777216
    float*          v2    = (float*)(ws + 98828288);          // 16777216
    float*          resb  = (float*)(ws + 115605504);         // 16777216
    if (ws_size < 132382720) return;                          // need ~126 MB

    // K1: qkv = x @ Wqkv + bqkv
    sgemm_bias<<<dim3(1536 / 128, 8192 / 128), 256, 0, stream>>>(
        x, Wqkv, bqkv, qkvb, 8192, 1536, 512);

    // K2: scores -> exact top-64(+ties) -> softmax -> sparse rows
    // 4096 blocks x 512 threads; 16 rows/block; XCD-affine bh mapping
    scores_topk<<<4096, 512, 0, stream>>>(qkvb, svals, sidxp, scntp);

    // K3 x3: polynomial filter (sparse A applications)
    spmm<<<16384, 256, 0, stream>>>(svals, sidxp, scntp, qkvb, nullptr, v1, resb, alphas, 0);
    spmm<<<16384, 256, 0, stream>>>(svals, sidxp, scntp, qkvb, v1, v2, resb, alphas, 1);
    spmm<<<16384, 256, 0, stream>>>(svals, sidxp, scntp, qkvb, v2, nullptr, resb, alphas, 2);

    // K4: out = res @ Wout + bout
    sgemm_bias<<<dim3(512 / 128, 8192 / 128), 256, 0, stream>>>(
        resb, Wout, bout, out, 8192, 512, 512);
}

// Round 9
// 1430.922 us; speedup vs baseline: 2.6834x; 1.1311x over previous
//
#include <hip/hip_runtime.h>
#include <hip/hip_bf16.h>

// Problem constants: B=4, N=2048, DIM=512, H=8, DH=64, ORDER=3, TOPK=64, INNER=512
#define SLOTS 80   // sparse slots per row (64 + tie headroom)

// ---------------------------------------------------------------------------
// K1/K4: fp32 tiled GEMM with bias: C = A(MxK) @ B(KxN) + bias(N)
// BM=BN=128, BK=16, 256 threads, 8x8 per thread. (unchanged)
// ---------------------------------------------------------------------------
__global__ __launch_bounds__(256)
void sgemm_bias(const float* __restrict__ A, const float* __restrict__ Bm,
                const float* __restrict__ bias, float* __restrict__ C,
                int M, int N, int K)
{
    __shared__ float As[16][132];
    __shared__ float Bs[16][132];

    const int t  = threadIdx.x;
    const int tx = t & 15, ty = t >> 4;
    const int bm = blockIdx.y << 7, bn = blockIdx.x << 7;

    const int arow = t >> 2,  ak4 = (t & 3) << 2;
    const int bkr  = t >> 5,  bc4 = (t & 31) << 2;

    float4 pa[2], pb[2];
#pragma unroll
    for (int s = 0; s < 2; ++s) {
        pa[s] = *(const float4*)&A[(size_t)(bm + arow + (s << 6)) * K + ak4];
        pb[s] = *(const float4*)&Bm[(size_t)(bkr + (s << 3)) * N + bn + bc4];
    }

    float acc[8][8] = {};

    for (int k0 = 0; k0 < K; k0 += 16) {
        __syncthreads();
#pragma unroll
        for (int s = 0; s < 2; ++s) {
            const int ar = arow + (s << 6);
            As[ak4 + 0][ar] = pa[s].x;
            As[ak4 + 1][ar] = pa[s].y;
            As[ak4 + 2][ar] = pa[s].z;
            As[ak4 + 3][ar] = pa[s].w;
            *(float4*)&Bs[bkr + (s << 3)][bc4] = pb[s];
        }
        __syncthreads();
        if (k0 + 16 < K) {
#pragma unroll
            for (int s = 0; s < 2; ++s) {
                pa[s] = *(const float4*)&A[(size_t)(bm + arow + (s << 6)) * K + k0 + 16 + ak4];
                pb[s] = *(const float4*)&Bm[(size_t)(k0 + 16 + bkr + (s << 3)) * N + bn + bc4];
            }
        }
#pragma unroll
        for (int kk = 0; kk < 16; ++kk) {
            float4 a0 = *(const float4*)&As[kk][(ty << 3) + 0];
            float4 a1 = *(const float4*)&As[kk][(ty << 3) + 4];
            float4 b0 = *(const float4*)&Bs[kk][(tx << 2)];
            float4 b1 = *(const float4*)&Bs[kk][64 + (tx << 2)];
            float ar[8] = {a0.x, a0.y, a0.z, a0.w, a1.x, a1.y, a1.z, a1.w};
            float br[8] = {b0.x, b0.y, b0.z, b0.w, b1.x, b1.y, b1.z, b1.w};
#pragma unroll
            for (int i = 0; i < 8; ++i)
#pragma unroll
                for (int j = 0; j < 8; ++j)
                    acc[i][j] = fmaf(ar[i], br[j], acc[i][j]);
        }
    }

    float bb[8];
#pragma unroll
    for (int j = 0; j < 4; ++j) {
        bb[j]     = bias[bn + (tx << 2) + j];
        bb[j + 4] = bias[bn + 64 + (tx << 2) + j];
    }
#pragma unroll
    for (int i = 0; i < 8; ++i) {
        const size_t row = (size_t)(bm + (ty << 3) + i);
        float4 o0 = {acc[i][0] + bb[0], acc[i][1] + bb[1], acc[i][2] + bb[2], acc[i][3] + bb[3]};
        float4 o1 = {acc[i][4] + bb[4], acc[i][5] + bb[5], acc[i][6] + bb[6], acc[i][7] + bb[7]};
        *(float4*)&C[row * N + bn + (tx << 2)]      = o0;
        *(float4*)&C[row * N + bn + 64 + (tx << 2)] = o1;
    }
}

// ---------------------------------------------------------------------------
// K2 v9: like R8 (clean, spill-free) but with CACHE-LINE-LINEAR K reads:
// the d-loop is split into 4 groups of 16; per group each lane loads its 4
// columns' full 64B chunk (4 consecutive float4 = one L1 line) into kv regs,
// then runs 1024 FMAs from registers. L1-miss traffic per block drops
// 2 MB -> 512 KB (panel read exactly once), and each group's load latency is
// amortized over 2048 cycles of FMA.
// All register arrays literal-indexed (rule #20). Per-score fmaf chain is
// d-ascending 0..63 -> bit-identical to R2-R8.
// ---------------------------------------------------------------------------
__global__ __launch_bounds__(512, 2)
void scores_topk(const float* __restrict__ qkv, float* __restrict__ svals,
                 unsigned short* __restrict__ sidx, int* __restrict__ scnt)
{
    __shared__ float S[16][2048];   // 128 KiB

    const int t    = threadIdx.x;
    const int lane = t & 63;
    const int wid  = t >> 6;                        // 0..7
    const int id   = blockIdx.x;                    // 0..4095
    const int bh   = ((id >> 10) << 3) | (id & 7);  // XCD-affine, bijective
    const int rowblk = (id >> 3) & 127;
    const int b = bh >> 3, h = bh & 7;
    const size_t rowbase = (size_t)b * 2048;
    const int r0 = rowblk << 4;                     // block's 16 rows

    // q base for the block's rows (uniform across lanes -> scalar loads)
    const float* qb = qkv + (rowbase + r0) * 1536 + (h << 6);
    // lane's 4 K-columns: cbase + {0,64,128,192}
    const int cbase = (wid << 8) + lane;
    const float* k0 = qkv + (rowbase + (size_t)cbase) * 1536 + 512 + (h << 6);

    float acc[16][4];
#pragma unroll
    for (int r = 0; r < 16; ++r)
#pragma unroll
        for (int c = 0; c < 4; ++c) acc[r][c] = 0.f;

#pragma unroll 1
    for (int sg = 0; sg < 4; ++sg) {
        // load each column's full 64B chunk (4 consecutive float4: same line)
        float4 kv0[4], kv1[4], kv2[4], kv3[4];
#pragma unroll
        for (int j = 0; j < 4; ++j) {
            kv0[j] = *(const float4*)&k0[             (sg << 4) + (j << 2)];
            kv1[j] = *(const float4*)&k0[ 64 * 1536 + (sg << 4) + (j << 2)];
            kv2[j] = *(const float4*)&k0[128 * 1536 + (sg << 4) + (j << 2)];
            kv3[j] = *(const float4*)&k0[192 * 1536 + (sg << 4) + (j << 2)];
        }
#pragma unroll
        for (int ss = 0; ss < 4; ++ss) {
#pragma unroll
            for (int r = 0; r < 16; ++r) {
                const float4 q4 = *(const float4*)&qb[r * 1536 + (sg << 4) + (ss << 2)];
                float a0 = acc[r][0], a1 = acc[r][1], a2 = acc[r][2], a3 = acc[r][3];
                a0 = fmaf(q4.x, kv0[ss].x, a0); a0 = fmaf(q4.y, kv0[ss].y, a0);
                a0 = fmaf(q4.z, kv0[ss].z, a0); a0 = fmaf(q4.w, kv0[ss].w, a0);
                a1 = fmaf(q4.x, kv1[ss].x, a1); a1 = fmaf(q4.y, kv1[ss].y, a1);
                a1 = fmaf(q4.z, kv1[ss].z, a1); a1 = fmaf(q4.w, kv1[ss].w, a1);
                a2 = fmaf(q4.x, kv2[ss].x, a2); a2 = fmaf(q4.y, kv2[ss].y, a2);
                a2 = fmaf(q4.z, kv2[ss].z, a2); a2 = fmaf(q4.w, kv2[ss].w, a2);
                a3 = fmaf(q4.x, kv3[ss].x, a3); a3 = fmaf(q4.y, kv3[ss].y, a3);
                a3 = fmaf(q4.z, kv3[ss].z, a3); a3 = fmaf(q4.w, kv3[ss].w, a3);
                acc[r][0] = a0; acc[r][1] = a1; acc[r][2] = a2; acc[r][3] = a3;
            }
        }
    }

    // flush scaled scores to S (consecutive lanes -> consecutive addresses)
#pragma unroll
    for (int r = 0; r < 16; ++r) {
        S[r][cbase +   0] = acc[r][0] * 0.125f;
        S[r][cbase +  64] = acc[r][1] * 0.125f;
        S[r][cbase + 128] = acc[r][2] * 0.125f;
        S[r][cbase + 192] = acc[r][3] * 0.125f;
    }
    __syncthreads();

    // phase B: per wave, 2 rows; exact 64th-largest via bit bisection
    const unsigned long long pre64 = (1ull << lane) - 1ull;

#define PHASEB(RQ)                                                             \
    {                                                                          \
        const int rr = (wid << 1) + (RQ);                                      \
        float    fv[32];                                                       \
        unsigned uv[32];                                                       \
        _Pragma("unroll")                                                      \
        for (int m = 0; m < 32; ++m) {                                         \
            const float x = S[rr][lane + (m << 6)];                            \
            fv[m] = x;                                                         \
            const unsigned bx = __float_as_uint(x);                            \
            uv[m] = bx ^ (unsigned)(((int)bx >> 31) | 0x80000000);             \
        }                                                                      \
        unsigned lo = 0;                                                       \
        _Pragma("unroll 1")                                                    \
        for (int bit = 31; bit >= 0; --bit) {                                  \
            const unsigned mid = lo | (1u << bit);                             \
            int c = 0;                                                         \
            _Pragma("unroll")                                                  \
            for (int m = 0; m < 32; ++m)                                       \
                c += __popcll(__ballot(uv[m] >= mid));                         \
            if (c >= 64) lo = mid;                                             \
        }                                                                      \
        unsigned um = 0;                                                       \
        _Pragma("unroll")                                                      \
        for (int m = 0; m < 32; ++m) um = uv[m] > um ? uv[m] : um;             \
        _Pragma("unroll")                                                      \
        for (int off = 1; off < 64; off <<= 1) {                               \
            const unsigned o = (unsigned)__shfl_xor((int)um, off, 64);         \
            um = o > um ? o : um;                                              \
        }                                                                      \
        const unsigned mbm = (um & 0x80000000u) ? (um ^ 0x80000000u) : ~um;    \
        const float Mx = __uint_as_float(mbm);                                 \
        float zs = 0.f;                                                        \
        _Pragma("unroll")                                                      \
        for (int m = 0; m < 32; ++m) {                                         \
            const bool keep = uv[m] >= lo;                                     \
            const float ex = keep ? __expf(fv[m] - Mx) : 0.f;                  \
            fv[m] = ex;                                                        \
            zs += ex;                                                          \
        }                                                                      \
        _Pragma("unroll")                                                      \
        for (int off = 1; off < 64; off <<= 1) zs += __shfl_xor(zs, off, 64);  \
        const float zinv = 1.0f / zs;                                          \
        const size_t grow = (size_t)bh * 2048 + r0 + rr;                       \
        float* vd          = svals + grow * SLOTS;                             \
        unsigned short* id = sidx  + grow * SLOTS;                             \
        int base = 0;                                                          \
        _Pragma("unroll")                                                      \
        for (int m = 0; m < 32; ++m) {                                         \
            const bool keep = uv[m] >= lo;                                     \
            unsigned long long ball = __ballot(keep);                          \
            if (keep) {                                                        \
                const int my = base + __popcll(ball & pre64);                  \
                if (my < SLOTS) {                                              \
                    vd[my] = fv[m] * zinv;                                     \
                    id[my] = (unsigned short)(lane + (m << 6));                \
                }                                                              \
            }                                                                  \
            base += __popcll(ball);                                            \
        }                                                                      \
        if (lane == 0) scnt[grow] = base < SLOTS ? base : SLOTS;               \
    }

    PHASEB(0)
    PHASEB(1)
#undef PHASEB
}

// ---------------------------------------------------------------------------
// K3: sparse attn application (unchanged).
// ---------------------------------------------------------------------------
__global__ __launch_bounds__(256)
void spmm(const float* __restrict__ svals, const unsigned short* __restrict__ sidx,
          const int* __restrict__ scnt, const float* __restrict__ qkv,
          const float* __restrict__ vin, float* __restrict__ vout,
          float* __restrict__ res, const float* __restrict__ alphas_raw, int order)
{
    const int lane = threadIdx.x & 63;
    const int gr   = (blockIdx.x << 2) + (threadIdx.x >> 6);  // 0..65535
    const int bh   = gr >> 11, n = gr & 2047;
    const int b    = bh >> 3,  h = bh & 7;

    const float* vb;
    int stride;
    if (order == 0) { vb = qkv + (size_t)b * 2048 * 1536 + 1024 + (h << 6); stride = 1536; }
    else            { vb = vin + ((size_t)bh << 17);                        stride = 64;   }

    const int cnt = scnt[gr];
    const float* va          = svals + (size_t)gr * SLOTS;
    const unsigned short* ia = sidx  + (size_t)gr * SLOTS;

    float acc = 0.f;
    int j = 0;
    for (; j + 4 <= cnt; j += 4) {
        float a0 = va[j], a1 = va[j + 1], a2 = va[j + 2], a3 = va[j + 3];
        int   i0 = ia[j], i1 = ia[j + 1], i2 = ia[j + 2], i3 = ia[j + 3];
        acc += a0 * vb[(size_t)i0 * stride + lane];
        acc += a1 * vb[(size_t)i1 * stride + lane];
        acc += a2 * vb[(size_t)i2 * stride + lane];
        acc += a3 * vb[(size_t)i3 * stride + lane];
    }
    for (; j < cnt; ++j) acc += va[j] * vb[(size_t)ia[j] * stride + lane];

    if (order < 2) vout[((size_t)gr << 6) + lane] = acc;

    float ar    = alphas_raw[(order << 3) + h];
    float alpha = ar * 0.5f * (1.0f + erff(ar * 0.70710678f));  // exact gelu
    size_t ro = ((size_t)b * 2048 + n) * 512 + (h << 6) + lane;
    float av  = alpha * acc;
    if (order == 0) res[ro] = av;
    else            res[ro] += av;
}

// ---------------------------------------------------------------------------
extern "C" void kernel_launch(void* const* d_in, const int* in_sizes, int n_in,
                              void* d_out, int out_size, void* d_ws, size_t ws_size,
                              hipStream_t stream)
{
    const float* x      = (const float*)d_in[0];
    const float* Wqkv   = (const float*)d_in[1];
    const float* bqkv   = (const float*)d_in[2];
    const float* Wout   = (const float*)d_in[3];
    const float* bout   = (const float*)d_in[4];
    const float* alphas = (const float*)d_in[5];
    float* out = (float*)d_out;

    // workspace layout (bytes)
    char* ws = (char*)d_ws;
    float*          qkvb  = (float*)ws;                       // 8192*1536*4 = 50331648
    float*          svals = (float*)(ws + 50331648);          // 65536*80*4  = 20971520
    unsigned short* sidxp = (unsigned short*)(ws + 71303168); // 65536*80*2  = 10485760
    int*            scntp = (int*)(ws + 81788928);            // 65536*4     = 262144
    float*          v1    = (float*)(ws + 82051072);          // 16777216
    float*          v2    = (float*)(ws + 98828288);          // 16777216
    float*          resb  = (float*)(ws + 115605504);         // 16777216
    if (ws_size < 132382720) return;                          // need ~126 MB

    // K1: qkv = x @ Wqkv + bqkv
    sgemm_bias<<<dim3(1536 / 128, 8192 / 128), 256, 0, stream>>>(
        x, Wqkv, bqkv, qkvb, 8192, 1536, 512);

    // K2: scores -> exact top-64(+ties) -> softmax -> sparse rows
    // 4096 blocks x 512 threads; 16 rows/block; XCD-affine bh mapping
    scores_topk<<<4096, 512, 0, stream>>>(qkvb, svals, sidxp, scntp);

    // K3 x3: polynomial filter (sparse A applications)
    spmm<<<16384, 256, 0, stream>>>(svals, sidxp, scntp, qkvb, nullptr, v1, resb, alphas, 0);
    spmm<<<16384, 256, 0, stream>>>(svals, sidxp, scntp, qkvb, v1, v2, resb, alphas, 1);
    spmm<<<16384, 256, 0, stream>>>(svals, sidxp, scntp, qkvb, v2, nullptr, resb, alphas, 2);

    // K4: out = res @ Wout + bout
    sgemm_bias<<<dim3(512 / 128, 8192 / 128), 256, 0, stream>>>(
        resb, Wout, bout, out, 8192, 512, 512);
}

// Round 10
// 1245.388 us; speedup vs baseline: 3.0831x; 1.1490x over previous
//
#include <hip/hip_runtime.h>
#include <hip/hip_bf16.h>

// Problem constants: B=4, N=2048, DIM=512, H=8, DH=64, ORDER=3, TOPK=64, INNER=512
#define SLOTS 80   // sparse slots per row (64 + tie headroom)

// ---------------------------------------------------------------------------
// K1/K4: fp32 tiled GEMM with bias: C = A(MxK) @ B(KxN) + bias(N)
// BM=BN=128, BK=16, 256 threads, 8x8 per thread. (unchanged)
// ---------------------------------------------------------------------------
__global__ __launch_bounds__(256)
void sgemm_bias(const float* __restrict__ A, const float* __restrict__ Bm,
                const float* __restrict__ bias, float* __restrict__ C,
                int M, int N, int K)
{
    __shared__ float As[16][132];
    __shared__ float Bs[16][132];

    const int t  = threadIdx.x;
    const int tx = t & 15, ty = t >> 4;
    const int bm = blockIdx.y << 7, bn = blockIdx.x << 7;

    const int arow = t >> 2,  ak4 = (t & 3) << 2;
    const int bkr  = t >> 5,  bc4 = (t & 31) << 2;

    float4 pa[2], pb[2];
#pragma unroll
    for (int s = 0; s < 2; ++s) {
        pa[s] = *(const float4*)&A[(size_t)(bm + arow + (s << 6)) * K + ak4];
        pb[s] = *(const float4*)&Bm[(size_t)(bkr + (s << 3)) * N + bn + bc4];
    }

    float acc[8][8] = {};

    for (int k0 = 0; k0 < K; k0 += 16) {
        __syncthreads();
#pragma unroll
        for (int s = 0; s < 2; ++s) {
            const int ar = arow + (s << 6);
            As[ak4 + 0][ar] = pa[s].x;
            As[ak4 + 1][ar] = pa[s].y;
            As[ak4 + 2][ar] = pa[s].z;
            As[ak4 + 3][ar] = pa[s].w;
            *(float4*)&Bs[bkr + (s << 3)][bc4] = pb[s];
        }
        __syncthreads();
        if (k0 + 16 < K) {
#pragma unroll
            for (int s = 0; s < 2; ++s) {
                pa[s] = *(const float4*)&A[(size_t)(bm + arow + (s << 6)) * K + k0 + 16 + ak4];
                pb[s] = *(const float4*)&Bm[(size_t)(k0 + 16 + bkr + (s << 3)) * N + bn + bc4];
            }
        }
#pragma unroll
        for (int kk = 0; kk < 16; ++kk) {
            float4 a0 = *(const float4*)&As[kk][(ty << 3) + 0];
            float4 a1 = *(const float4*)&As[kk][(ty << 3) + 4];
            float4 b0 = *(const float4*)&Bs[kk][(tx << 2)];
            float4 b1 = *(const float4*)&Bs[kk][64 + (tx << 2)];
            float ar[8] = {a0.x, a0.y, a0.z, a0.w, a1.x, a1.y, a1.z, a1.w};
            float br[8] = {b0.x, b0.y, b0.z, b0.w, b1.x, b1.y, b1.z, b1.w};
#pragma unroll
            for (int i = 0; i < 8; ++i)
#pragma unroll
                for (int j = 0; j < 8; ++j)
                    acc[i][j] = fmaf(ar[i], br[j], acc[i][j]);
        }
    }

    float bb[8];
#pragma unroll
    for (int j = 0; j < 4; ++j) {
        bb[j]     = bias[bn + (tx << 2) + j];
        bb[j + 4] = bias[bn + 64 + (tx << 2) + j];
    }
#pragma unroll
    for (int i = 0; i < 8; ++i) {
        const size_t row = (size_t)(bm + (ty << 3) + i);
        float4 o0 = {acc[i][0] + bb[0], acc[i][1] + bb[1], acc[i][2] + bb[2], acc[i][3] + bb[3]};
        float4 o1 = {acc[i][4] + bb[4], acc[i][5] + bb[5], acc[i][6] + bb[6], acc[i][7] + bb[7]};
        *(float4*)&C[row * N + bn + (tx << 2)]      = o0;
        *(float4*)&C[row * N + bn + 64 + (tx << 2)] = o1;
    }
}

// ---------------------------------------------------------------------------
// K2 v10: R9's clean structure at HALF the block: 512 threads own 8 rows,
// S[8][2048] = 64 KB -> 2 blocks/CU (4 waves/SIMD). Two co-resident blocks
// overlap one block's phase-B serial chains with the other's QK^T load
// latency. Lane owns 4 cols (t, 512+t, 1024+t, 1536+t); cache-line-linear
// K reads (64B chunk per col per d-group). Phase B = 1 row per wave.
// Same fmaf chain (d-ascending), same S layout, same phase-B math and
// compaction order -> bit-identical output to R8/R9.
// ---------------------------------------------------------------------------
__global__ __launch_bounds__(512, 4)
void scores_topk(const float* __restrict__ qkv, float* __restrict__ svals,
                 unsigned short* __restrict__ sidx, int* __restrict__ scnt)
{
    __shared__ float S[8][2048];   // 64 KiB

    const int t    = threadIdx.x;
    const int lane = t & 63;
    const int wid  = t >> 6;                        // 0..7
    const int id   = blockIdx.x;                    // 0..8191
    const int bh   = ((id >> 11) << 3) | (id & 7);  // XCD-affine, bijective
    const int rowblk = (id >> 3) & 255;
    const int b = bh >> 3, h = bh & 7;
    const size_t rowbase = (size_t)b * 2048;
    const int r0 = rowblk << 3;                     // block's 8 rows

    // q base for the block's rows (uniform across lanes -> scalar loads)
    const float* qb = qkv + (rowbase + r0) * 1536 + (h << 6);
    // lane's 4 K-columns: t + {0, 512, 1024, 1536}
    const float* k0 = qkv + (rowbase + (size_t)t) * 1536 + 512 + (h << 6);

    float acc[8][4];
#pragma unroll
    for (int r = 0; r < 8; ++r)
#pragma unroll
        for (int c = 0; c < 4; ++c) acc[r][c] = 0.f;

#pragma unroll 1
    for (int sg = 0; sg < 4; ++sg) {
        // load each column's full 64B chunk (4 consecutive float4: same line)
        float4 kv0[4], kv1[4], kv2[4], kv3[4];
#pragma unroll
        for (int j = 0; j < 4; ++j) {
            kv0[j] = *(const float4*)&k0[                   (sg << 4) + (j << 2)];
            kv1[j] = *(const float4*)&k0[ 512 * 1536 +      (sg << 4) + (j << 2)];
            kv2[j] = *(const float4*)&k0[1024 * 1536 +      (sg << 4) + (j << 2)];
            kv3[j] = *(const float4*)&k0[1536 * 1536 +      (sg << 4) + (j << 2)];
        }
#pragma unroll
        for (int ss = 0; ss < 4; ++ss) {
#pragma unroll
            for (int r = 0; r < 8; ++r) {
                const float4 q4 = *(const float4*)&qb[r * 1536 + (sg << 4) + (ss << 2)];
                float a0 = acc[r][0], a1 = acc[r][1], a2 = acc[r][2], a3 = acc[r][3];
                a0 = fmaf(q4.x, kv0[ss].x, a0); a0 = fmaf(q4.y, kv0[ss].y, a0);
                a0 = fmaf(q4.z, kv0[ss].z, a0); a0 = fmaf(q4.w, kv0[ss].w, a0);
                a1 = fmaf(q4.x, kv1[ss].x, a1); a1 = fmaf(q4.y, kv1[ss].y, a1);
                a1 = fmaf(q4.z, kv1[ss].z, a1); a1 = fmaf(q4.w, kv1[ss].w, a1);
                a2 = fmaf(q4.x, kv2[ss].x, a2); a2 = fmaf(q4.y, kv2[ss].y, a2);
                a2 = fmaf(q4.z, kv2[ss].z, a2); a2 = fmaf(q4.w, kv2[ss].w, a2);
                a3 = fmaf(q4.x, kv3[ss].x, a3); a3 = fmaf(q4.y, kv3[ss].y, a3);
                a3 = fmaf(q4.z, kv3[ss].z, a3); a3 = fmaf(q4.w, kv3[ss].w, a3);
                acc[r][0] = a0; acc[r][1] = a1; acc[r][2] = a2; acc[r][3] = a3;
            }
        }
    }

    // flush scaled scores to S (consecutive lanes -> consecutive addresses)
#pragma unroll
    for (int r = 0; r < 8; ++r) {
        S[r][t +    0] = acc[r][0] * 0.125f;
        S[r][t +  512] = acc[r][1] * 0.125f;
        S[r][t + 1024] = acc[r][2] * 0.125f;
        S[r][t + 1536] = acc[r][3] * 0.125f;
    }
    __syncthreads();

    // phase B: ONE row per wave (rr = wid); exact 64th-largest via bisection
    const unsigned long long pre64 = (1ull << lane) - 1ull;
    {
        const int rr = wid;
        float    fv[32];
        unsigned uv[32];
#pragma unroll
        for (int m = 0; m < 32; ++m) {
            const float x = S[rr][lane + (m << 6)];
            fv[m] = x;
            const unsigned bx = __float_as_uint(x);
            uv[m] = bx ^ (unsigned)(((int)bx >> 31) | 0x80000000);
        }
        unsigned lo = 0;
#pragma unroll 1
        for (int bit = 31; bit >= 0; --bit) {
            const unsigned mid = lo | (1u << bit);
            int c = 0;
#pragma unroll
            for (int m = 0; m < 32; ++m)
                c += __popcll(__ballot(uv[m] >= mid));
            if (c >= 64) lo = mid;   // uniform (ballot count is wave-uniform)
        }
        unsigned um = 0;
#pragma unroll
        for (int m = 0; m < 32; ++m) um = uv[m] > um ? uv[m] : um;
#pragma unroll
        for (int off = 1; off < 64; off <<= 1) {
            const unsigned o = (unsigned)__shfl_xor((int)um, off, 64);
            um = o > um ? o : um;
        }
        const unsigned mbm = (um & 0x80000000u) ? (um ^ 0x80000000u) : ~um;
        const float Mx = __uint_as_float(mbm);

        float zs = 0.f;
#pragma unroll
        for (int m = 0; m < 32; ++m) {
            const bool keep = uv[m] >= lo;
            const float ex = keep ? __expf(fv[m] - Mx) : 0.f;
            fv[m] = ex;
            zs += ex;
        }
#pragma unroll
        for (int off = 1; off < 64; off <<= 1) zs += __shfl_xor(zs, off, 64);
        const float zinv = 1.0f / zs;

        const size_t grow = (size_t)bh * 2048 + r0 + rr;
        float* vd          = svals + grow * SLOTS;
        unsigned short* id2 = nullptr;
        (void)id2;
        unsigned short* idp = sidx + grow * SLOTS;
        int base = 0;
#pragma unroll
        for (int m = 0; m < 32; ++m) {
            const bool keep = uv[m] >= lo;
            unsigned long long ball = __ballot(keep);
            if (keep) {
                const int my = base + __popcll(ball & pre64);
                if (my < SLOTS) {
                    vd[my]  = fv[m] * zinv;
                    idp[my] = (unsigned short)(lane + (m << 6));
                }
            }
            base += __popcll(ball);
        }
        if (lane == 0) scnt[grow] = base < SLOTS ? base : SLOTS;
    }
}

// ---------------------------------------------------------------------------
// K3: sparse attn application (unchanged).
// ---------------------------------------------------------------------------
__global__ __launch_bounds__(256)
void spmm(const float* __restrict__ svals, const unsigned short* __restrict__ sidx,
          const int* __restrict__ scnt, const float* __restrict__ qkv,
          const float* __restrict__ vin, float* __restrict__ vout,
          float* __restrict__ res, const float* __restrict__ alphas_raw, int order)
{
    const int lane = threadIdx.x & 63;
    const int gr   = (blockIdx.x << 2) + (threadIdx.x >> 6);  // 0..65535
    const int bh   = gr >> 11, n = gr & 2047;
    const int b    = bh >> 3,  h = bh & 7;

    const float* vb;
    int stride;
    if (order == 0) { vb = qkv + (size_t)b * 2048 * 1536 + 1024 + (h << 6); stride = 1536; }
    else            { vb = vin + ((size_t)bh << 17);                        stride = 64;   }

    const int cnt = scnt[gr];
    const float* va          = svals + (size_t)gr * SLOTS;
    const unsigned short* ia = sidx  + (size_t)gr * SLOTS;

    float acc = 0.f;
    int j = 0;
    for (; j + 4 <= cnt; j += 4) {
        float a0 = va[j], a1 = va[j + 1], a2 = va[j + 2], a3 = va[j + 3];
        int   i0 = ia[j], i1 = ia[j + 1], i2 = ia[j + 2], i3 = ia[j + 3];
        acc += a0 * vb[(size_t)i0 * stride + lane];
        acc += a1 * vb[(size_t)i1 * stride + lane];
        acc += a2 * vb[(size_t)i2 * stride + lane];
        acc += a3 * vb[(size_t)i3 * stride + lane];
    }
    for (; j < cnt; ++j) acc += va[j] * vb[(size_t)ia[j] * stride + lane];

    if (order < 2) vout[((size_t)gr << 6) + lane] = acc;

    float ar    = alphas_raw[(order << 3) + h];
    float alpha = ar * 0.5f * (1.0f + erff(ar * 0.70710678f));  // exact gelu
    size_t ro = ((size_t)b * 2048 + n) * 512 + (h << 6) + lane;
    float av  = alpha * acc;
    if (order == 0) res[ro] = av;
    else            res[ro] += av;
}

// ---------------------------------------------------------------------------
extern "C" void kernel_launch(void* const* d_in, const int* in_sizes, int n_in,
                              void* d_out, int out_size, void* d_ws, size_t ws_size,
                              hipStream_t stream)
{
    const float* x      = (const float*)d_in[0];
    const float* Wqkv   = (const float*)d_in[1];
    const float* bqkv   = (const float*)d_in[2];
    const float* Wout   = (const float*)d_in[3];
    const float* bout   = (const float*)d_in[4];
    const float* alphas = (const float*)d_in[5];
    float* out = (float*)d_out;

    // workspace layout (bytes)
    char* ws = (char*)d_ws;
    float*          qkvb  = (float*)ws;                       // 8192*1536*4 = 50331648
    float*          svals = (float*)(ws + 50331648);          // 65536*80*4  = 20971520
    unsigned short* sidxp = (unsigned short*)(ws + 71303168); // 65536*80*2  = 10485760
    int*            scntp = (int*)(ws + 81788928);            // 65536*4     = 262144
    float*          v1    = (float*)(ws + 82051072);          // 16777216
    float*          v2    = (float*)(ws + 98828288);          // 16777216
    float*          resb  = (float*)(ws + 115605504);         // 16777216
    if (ws_size < 132382720) return;                          // need ~126 MB

    // K1: qkv = x @ Wqkv + bqkv
    sgemm_bias<<<dim3(1536 / 128, 8192 / 128), 256, 0, stream>>>(
        x, Wqkv, bqkv, qkvb, 8192, 1536, 512);

    // K2: scores -> exact top-64(+ties) -> softmax -> sparse rows
    // 8192 blocks x 512 threads; 8 rows/block; XCD-affine bh mapping
    scores_topk<<<8192, 512, 0, stream>>>(qkvb, svals, sidxp, scntp);

    // K3 x3: polynomial filter (sparse A applications)
    spmm<<<16384, 256, 0, stream>>>(svals, sidxp, scntp, qkvb, nullptr, v1, resb, alphas, 0);
    spmm<<<16384, 256, 0, stream>>>(svals, sidxp, scntp, qkvb, v1, v2, resb, alphas, 1);
    spmm<<<16384, 256, 0, stream>>>(svals, sidxp, scntp, qkvb, v2, nullptr, resb, alphas, 2);

    // K4: out = res @ Wout + bout
    sgemm_bias<<<dim3(512 / 128, 8192 / 128), 256, 0, stream>>>(
        resb, Wout, bout, out, 8192, 512, 512);
}